// Round 3
// baseline (501.045 us; speedup 1.0000x reference)
//
#include <hip/hip_runtime.h>

#define DD 64

// ---------------------------------------------------------------------------
// Detect whether edge_index arrived as int64 (little-endian high words == 0)
// or int32. Deterministic, runs every call.
// ---------------------------------------------------------------------------
__global__ void detect_i64_kernel(const unsigned int* __restrict__ p, int nPairs,
                                  int* __restrict__ flag) {
  if (blockIdx.x == 0 && threadIdx.x == 0) {
    int is64 = 1;
    int lim = nPairs < 128 ? nPairs : 128;
    for (int i = 0; i < lim; ++i) {
      if (p[2 * i + 1] != 0u) { is64 = 0; break; }
    }
    *flag = is64;
  }
}

__global__ void init_deg_kernel(int* __restrict__ deg, int n) {
  int i = blockIdx.x * blockDim.x + threadIdx.x;
  if (i < n) deg[i] = 1;   // self-loop
}

// count in-degree (edges only; self-loop pre-seeded by init_deg)
__global__ void count_kernel(const void* __restrict__ eidx, int E,
                             int* __restrict__ deg, const int* __restrict__ flag) {
  int e = blockIdx.x * blockDim.x + threadIdx.x;
  if (e >= E) return;
  int d;
  if (*flag) {
    const long long* p = (const long long*)eidx;
    d = (int)p[e + E];
  } else {
    const int* p = (const int*)eidx;
    d = p[e + E];
  }
  atomicAdd(&deg[d], 1);
}

__global__ void dinv_kernel(const int* __restrict__ deg, float* __restrict__ dinv, int n) {
  int i = blockIdx.x * blockDim.x + threadIdx.x;
  if (i < n) dinv[i] = rsqrtf((float)deg[i]);
}

// ---- hierarchical exclusive scan of deg -> offs (tile = 1024) --------------
__global__ void scan_tile_kernel(const int* __restrict__ deg, int* __restrict__ incl,
                                 int* __restrict__ bsum, int n) {
  __shared__ int s[1024];
  int tid = threadIdx.x;
  int i = blockIdx.x * 1024 + tid;
  int v = (i < n) ? deg[i] : 0;
  s[tid] = v;
  __syncthreads();
  for (int off = 1; off < 1024; off <<= 1) {
    int tv = (tid >= off) ? s[tid - off] : 0;
    __syncthreads();
    s[tid] += tv;
    __syncthreads();
  }
  if (i < n) incl[i] = s[tid];
  if (tid == 1023) bsum[blockIdx.x] = s[1023];
}

__global__ void scan_blocks_kernel(const int* __restrict__ bsum, int* __restrict__ boff,
                                   int nb, int* __restrict__ total_out) {
  if (blockIdx.x == 0 && threadIdx.x == 0) {
    int run = 0;
    for (int i = 0; i < nb; ++i) { boff[i] = run; run += bsum[i]; }
    *total_out = run;   // offs[n]
  }
}

__global__ void scan_final_kernel(const int* __restrict__ incl, const int* __restrict__ deg,
                                  const int* __restrict__ boff, int* __restrict__ offs,
                                  int* __restrict__ cursor, int n) {
  int i = blockIdx.x * blockDim.x + threadIdx.x;
  if (i >= n) return;
  int e = incl[i] - deg[i] + boff[i >> 10];
  offs[i] = e;
  cursor[i] = e;
}

// ---- CSR fill: col only (edges then self-loops) ----------------------------
__global__ void scatter_kernel(const void* __restrict__ eidx,
                               int* __restrict__ cursor,
                               int* __restrict__ col, int E, int n,
                               const int* __restrict__ flag) {
  int e = blockIdx.x * blockDim.x + threadIdx.x;
  if (e < E) {
    int s, d;
    if (*flag) {
      const long long* p = (const long long*)eidx;
      s = (int)p[e];
      d = (int)p[e + E];
    } else {
      const int* p = (const int*)eidx;
      s = p[e];
      d = p[e + E];
    }
    int pos = atomicAdd(&cursor[d], 1);
    col[pos] = s;
  } else if (e < E + n) {
    int m = e - E;
    int pos = atomicAdd(&cursor[m], 1);
    col[pos] = m;
  }
}

// ---- dense GEMM: T = H @ W (+bias+relu if fuse) (*dinv[row] if scale) ------
// block = 256 threads (16x16); 64 rows per block; W and H tile staged in LDS.
__global__ __launch_bounds__(256) void gemm_kernel(
    const float* __restrict__ H, const float* __restrict__ W,
    const float* __restrict__ bias, const float* __restrict__ dinv,
    float* __restrict__ T, int n, int fuse) {
  __shared__ float Ws[64][68];
  __shared__ float Hs[64][68];
  int tid = threadIdx.x;
  int row0 = blockIdx.x * 64;

  for (int i = tid; i < 1024; i += 256) {
    int r = i >> 4, c = (i & 15) << 2;
    float4 wv = ((const float4*)W)[i];
    *reinterpret_cast<float4*>(&Ws[r][c]) = wv;
    float4 hv = make_float4(0.f, 0.f, 0.f, 0.f);
    if (row0 + r < n)
      hv = *reinterpret_cast<const float4*>(H + (size_t)(row0 + r) * DD + c);
    *reinterpret_cast<float4*>(&Hs[r][c]) = hv;
  }
  __syncthreads();

  int tr = tid >> 4, tc = tid & 15;   // 16x16 thread grid
  int r0 = tr << 2, c0 = tc << 2;     // 4x4 tile at (r0, c0)

  float acc[4][4];
#pragma unroll
  for (int i = 0; i < 4; ++i)
#pragma unroll
    for (int j = 0; j < 4; ++j) acc[i][j] = 0.f;

#pragma unroll
  for (int k = 0; k < 64; ++k) {
    float h0 = Hs[r0 + 0][k];
    float h1 = Hs[r0 + 1][k];
    float h2 = Hs[r0 + 2][k];
    float h3 = Hs[r0 + 3][k];
    float4 wv = *reinterpret_cast<const float4*>(&Ws[k][c0]);
    acc[0][0] = fmaf(h0, wv.x, acc[0][0]);
    acc[0][1] = fmaf(h0, wv.y, acc[0][1]);
    acc[0][2] = fmaf(h0, wv.z, acc[0][2]);
    acc[0][3] = fmaf(h0, wv.w, acc[0][3]);
    acc[1][0] = fmaf(h1, wv.x, acc[1][0]);
    acc[1][1] = fmaf(h1, wv.y, acc[1][1]);
    acc[1][2] = fmaf(h1, wv.z, acc[1][2]);
    acc[1][3] = fmaf(h1, wv.w, acc[1][3]);
    acc[2][0] = fmaf(h2, wv.x, acc[2][0]);
    acc[2][1] = fmaf(h2, wv.y, acc[2][1]);
    acc[2][2] = fmaf(h2, wv.z, acc[2][2]);
    acc[2][3] = fmaf(h2, wv.w, acc[2][3]);
    acc[3][0] = fmaf(h3, wv.x, acc[3][0]);
    acc[3][1] = fmaf(h3, wv.y, acc[3][1]);
    acc[3][2] = fmaf(h3, wv.z, acc[3][2]);
    acc[3][3] = fmaf(h3, wv.w, acc[3][3]);
  }

  float4 bv = make_float4(0.f, 0.f, 0.f, 0.f);
  if (fuse) bv = *reinterpret_cast<const float4*>(bias + c0);
#pragma unroll
  for (int i = 0; i < 4; ++i) {
    long long row = (long long)row0 + r0 + i;
    if (row >= n) break;
    float4 o = make_float4(acc[i][0], acc[i][1], acc[i][2], acc[i][3]);
    if (fuse) {
      o.x = fmaxf(o.x + bv.x, 0.f);
      o.y = fmaxf(o.y + bv.y, 0.f);
      o.z = fmaxf(o.z + bv.z, 0.f);
      o.w = fmaxf(o.w + bv.w, 0.f);
    }
    if (dinv) {
      float dv = dinv[row];
      o.x *= dv; o.y *= dv; o.z *= dv; o.w *= dv;
    }
    *reinterpret_cast<float4*>(T + (size_t)row * DD + c0) = o;
  }
}

// ---- CSR aggregation: out[d,:] = dinv[d] * sum_{c in N(d)} T'[c,:] + b -----
// one wave (64 lanes) per node, lane = feature dim. No atomics, no val array.
__global__ __launch_bounds__(256) void aggregate_kernel(
    const float* __restrict__ T, const int* __restrict__ offs,
    const int* __restrict__ col, const float* __restrict__ dinv,
    const float* __restrict__ bias, float* __restrict__ out,
    int n, int relu) {
  int gid = blockIdx.x * blockDim.x + threadIdx.x;
  int wid = gid >> 6;
  int lane = threadIdx.x & 63;
  if (wid >= n) return;
  int j0 = offs[wid], j1 = offs[wid + 1];
  float acc = 0.f;
  int j = j0;
  for (; j + 4 <= j1; j += 4) {
    int c0 = col[j], c1 = col[j + 1], c2 = col[j + 2], c3 = col[j + 3];
    float f0 = T[(size_t)c0 * DD + lane];
    float f1 = T[(size_t)c1 * DD + lane];
    float f2 = T[(size_t)c2 * DD + lane];
    float f3 = T[(size_t)c3 * DD + lane];
    acc += f0 + f1 + f2 + f3;
  }
  for (; j < j1; ++j)
    acc += T[(size_t)col[j] * DD + lane];
  acc = fmaf(acc, dinv[wid], bias[lane]);
  if (relu) acc = fmaxf(acc, 0.f);
  out[(size_t)wid * DD + lane] = acc;
}

// ---------------------------------------------------------------------------
extern "C" void kernel_launch(void* const* d_in, const int* in_sizes, int n_in,
                              void* d_out, int out_size, void* d_ws, size_t ws_size,
                              hipStream_t stream) {
  const float* x   = (const float*)d_in[0];
  const void*  eix = d_in[1];
  const float* Win = (const float*)d_in[2];
  const float* bin = (const float*)d_in[3];
  const float* W1  = (const float*)d_in[4];
  const float* b1  = (const float*)d_in[5];
  const float* W2  = (const float*)d_in[6];
  const float* b2  = (const float*)d_in[7];
  const float* W3  = (const float*)d_in[8];
  const float* b3  = (const float*)d_in[9];

  int n = in_sizes[0] / DD;
  int E = in_sizes[1] / 2;
  int M = E + n;

  char* w = (char*)d_ws;
  auto carve = [&](size_t bytes) {
    char* p = w;
    w += (bytes + 255) & ~(size_t)255;
    return p;
  };
  int*   flag   = (int*)carve(4);
  int*   deg    = (int*)carve((size_t)n * 4);
  float* dinv   = (float*)carve((size_t)n * 4);
  int*   incl   = (int*)carve((size_t)n * 4);
  int*   bsum   = (int*)carve(4096);
  int*   boff   = (int*)carve(4096);
  int*   offs   = (int*)carve((size_t)(n + 1) * 4);
  int*   cursor = (int*)carve((size_t)n * 4);
  int*   col    = (int*)carve((size_t)M * 4);
  float* hbuf   = (float*)carve((size_t)n * DD * 4);
  float* tbuf   = (float*)carve((size_t)n * DD * 4);

  int nb = (n + 1023) / 1024;

  detect_i64_kernel<<<1, 64, 0, stream>>>((const unsigned int*)eix, E, flag);
  init_deg_kernel<<<(n + 255) / 256, 256, 0, stream>>>(deg, n);
  count_kernel<<<(E + 255) / 256, 256, 0, stream>>>(eix, E, deg, flag);
  dinv_kernel<<<(n + 255) / 256, 256, 0, stream>>>(deg, dinv, n);
  scan_tile_kernel<<<nb, 1024, 0, stream>>>(deg, incl, bsum, n);
  scan_blocks_kernel<<<1, 64, 0, stream>>>(bsum, boff, nb, offs + n);
  scan_final_kernel<<<(n + 255) / 256, 256, 0, stream>>>(incl, deg, boff, offs, cursor, n);
  scatter_kernel<<<(M + 255) / 256, 256, 0, stream>>>(eix, cursor, col, E, n, flag);

  int gemm_grid = (n + 63) / 64;
  int agg_grid  = (n * 64 + 255) / 256;

  // layer 0: h = relu(x @ W_in + b_in)      (no dinv scale)
  gemm_kernel<<<gemm_grid, 256, 0, stream>>>(x, Win, bin, nullptr, hbuf, n, 1);

  // conv1: h = relu(dinv*agg(dinv*(h @ W1)) + b1)
  gemm_kernel<<<gemm_grid, 256, 0, stream>>>(hbuf, W1, nullptr, dinv, tbuf, n, 0);
  aggregate_kernel<<<agg_grid, 256, 0, stream>>>(tbuf, offs, col, dinv, b1, hbuf, n, 1);

  // conv2
  gemm_kernel<<<gemm_grid, 256, 0, stream>>>(hbuf, W2, nullptr, dinv, tbuf, n, 0);
  aggregate_kernel<<<agg_grid, 256, 0, stream>>>(tbuf, offs, col, dinv, b2, hbuf, n, 1);

  // conv3 (no relu)
  gemm_kernel<<<gemm_grid, 256, 0, stream>>>(hbuf, W3, nullptr, dinv, tbuf, n, 0);
  aggregate_kernel<<<agg_grid, 256, 0, stream>>>(tbuf, offs, col, dinv, b3, (float*)d_out, n, 0);
}

// Round 5
// 368.115 us; speedup vs baseline: 1.3611x; 1.3611x over previous
//
#include <hip/hip_runtime.h>

#define DD 64
#define NB 256          // buckets (one per passC block); requires n <= 65536
#define GB 128          // blocks for histA/passB

// ---------------------------------------------------------------------------
__global__ void detect_i64_kernel(const unsigned int* __restrict__ p, int nPairs,
                                  int* __restrict__ flag) {
  if (blockIdx.x == 0 && threadIdx.x == 0) {
    int is64 = 1;
    int lim = nPairs < 128 ? nPairs : 128;
    for (int i = 0; i < lim; ++i) {
      if (p[2 * i + 1] != 0u) { is64 = 0; break; }
    }
    *flag = is64;
  }
}

// ---- histA: per-(block,bucket) histogram of dst --------------------------
__global__ __launch_bounds__(256) void histA_kernel(
    const void* __restrict__ eidx, int E, int chunk,
    int* __restrict__ histPB, const int* __restrict__ flag) {
  __shared__ int h[NB];
  int tid = threadIdx.x;
  h[tid] = 0;
  __syncthreads();
  int seg = (E + GB - 1) / GB;
  int e0 = blockIdx.x * seg;
  int e1 = min(e0 + seg, E);
  int is64 = *flag;
  for (int e = e0 + tid; e < e1; e += 256) {
    int d;
    if (is64) d = (int)((const long long*)eidx)[e + E];
    else      d = ((const int*)eidx)[e + E];
    atomicAdd(&h[d / chunk], 1);
  }
  __syncthreads();
  histPB[blockIdx.x * NB + tid] = h[tid];
}

// ---- scanB: bucket bases, per-(block,bucket) bases, csr bases -------------
__global__ __launch_bounds__(NB) void scanB_kernel(
    const int* __restrict__ histPB, int* __restrict__ base_bb,
    int* __restrict__ bucketBase, int* __restrict__ csrBase,
    int* __restrict__ offs, int n, int E, int chunk) {
  __shared__ int sc[NB];
  int b = threadIdx.x;
  int tot = 0;
  for (int blk = 0; blk < GB; ++blk) tot += histPB[blk * NB + b];
  sc[b] = tot;
  __syncthreads();
  // inclusive Hillis-Steele scan
  for (int off = 1; off < NB; off <<= 1) {
    int t = (b >= off) ? sc[b - off] : 0;
    __syncthreads();
    sc[b] += t;
    __syncthreads();
  }
  int excl = sc[b] - tot;                 // exclusive prefix of bucket totals
  bucketBase[b] = excl;
  if (b == NB - 1) bucketBase[NB] = excl + tot;   // == E
  int dpre = b * chunk; if (dpre > n) dpre = n;
  csrBase[b] = excl + dpre;
  int run = excl;
  for (int blk = 0; blk < GB; ++blk) {
    base_bb[blk * NB + b] = run;
    run += histPB[blk * NB + b];
  }
  if (b == 0) offs[n] = E + n;
}

// ---- passB: bucketed scatter of packed records (src<<16 | local_dst) ------
__global__ __launch_bounds__(256) void passB_kernel(
    const void* __restrict__ eidx, int E, int chunk,
    const int* __restrict__ base_bb, unsigned int* __restrict__ rec,
    const int* __restrict__ flag) {
  __shared__ int cur[NB];
  int tid = threadIdx.x;
  cur[tid] = base_bb[blockIdx.x * NB + tid];
  __syncthreads();
  int seg = (E + GB - 1) / GB;
  int e0 = blockIdx.x * seg;
  int e1 = min(e0 + seg, E);
  int is64 = *flag;
  for (int e = e0 + tid; e < e1; e += 256) {
    int s, d;
    if (is64) {
      const long long* p = (const long long*)eidx;
      s = (int)p[e];
      d = (int)p[e + E];
    } else {
      const int* p = (const int*)eidx;
      s = p[e];
      d = p[e + E];
    }
    int b = d / chunk;
    int ld = d - b * chunk;
    int pos = atomicAdd(&cur[b], 1);
    rec[pos] = ((unsigned int)s << 16) | (unsigned int)ld;
  }
}

// ---- passC: per-bucket CSR finalize (offs, dinv, col) ---------------------
__global__ __launch_bounds__(256) void passC_kernel(
    const unsigned int* __restrict__ rec, const int* __restrict__ bucketBase,
    const int* __restrict__ csrBase, int* __restrict__ offs,
    float* __restrict__ dinv, int* __restrict__ col, int n, int chunk) {
  int b = blockIdx.x;
  int tid = threadIdx.x;
  int d0 = b * chunk;
  if (d0 >= n) return;
  int nd = min(chunk, n - d0);
  int jb0 = bucketBase[b], jb1 = bucketBase[b + 1];
  int cb = csrBase[b];

  __shared__ int hist[NB];
  __shared__ int sc[NB];
  __shared__ int cursor[NB];
  hist[tid] = (tid < nd) ? 1 : 0;   // self-loop seed
  __syncthreads();
  for (int j = jb0 + tid; j < jb1; j += 256)
    atomicAdd(&hist[rec[j] & 0xFFFFu], 1);
  __syncthreads();
  int deg = hist[tid];
  sc[tid] = deg;
  __syncthreads();
  for (int off = 1; off < NB; off <<= 1) {
    int t = (tid >= off) ? sc[tid - off] : 0;
    __syncthreads();
    sc[tid] += t;
    __syncthreads();
  }
  int loc = sc[tid] - deg;          // exclusive prefix
  if (tid < nd) {
    offs[d0 + tid] = cb + loc;
    dinv[d0 + tid] = rsqrtf((float)deg);
    col[cb + loc] = d0 + tid;       // self-loop first
  }
  cursor[tid] = loc + 1;
  __syncthreads();
  for (int j = jb0 + tid; j < jb1; j += 256) {
    unsigned int r = rec[j];
    int ld = (int)(r & 0xFFFFu);
    int s  = (int)(r >> 16);
    int p = atomicAdd(&cursor[ld], 1);
    col[cb + p] = s;
  }
}

// ---- dense GEMM: T = H @ W (+bias+relu if fuse) (*dinv[row] if scale) ------
__global__ __launch_bounds__(256) void gemm_kernel(
    const float* __restrict__ H, const float* __restrict__ W,
    const float* __restrict__ bias, const float* __restrict__ dinv,
    float* __restrict__ T, int n, int fuse) {
  __shared__ float Ws[64][68];
  __shared__ float Hs[64][68];
  int tid = threadIdx.x;
  int row0 = blockIdx.x * 64;

  for (int i = tid; i < 1024; i += 256) {
    int r = i >> 4, c = (i & 15) << 2;
    float4 wv = ((const float4*)W)[i];
    *reinterpret_cast<float4*>(&Ws[r][c]) = wv;
    float4 hv = make_float4(0.f, 0.f, 0.f, 0.f);
    if (row0 + r < n)
      hv = *reinterpret_cast<const float4*>(H + (size_t)(row0 + r) * DD + c);
    *reinterpret_cast<float4*>(&Hs[r][c]) = hv;
  }
  __syncthreads();

  int tr = tid >> 4, tc = tid & 15;
  int r0 = tr << 2, c0 = tc << 2;

  float acc[4][4];
#pragma unroll
  for (int i = 0; i < 4; ++i)
#pragma unroll
    for (int j = 0; j < 4; ++j) acc[i][j] = 0.f;

#pragma unroll
  for (int k = 0; k < 64; ++k) {
    float h0 = Hs[r0 + 0][k];
    float h1 = Hs[r0 + 1][k];
    float h2 = Hs[r0 + 2][k];
    float h3 = Hs[r0 + 3][k];
    float4 wv = *reinterpret_cast<const float4*>(&Ws[k][c0]);
    acc[0][0] = fmaf(h0, wv.x, acc[0][0]);
    acc[0][1] = fmaf(h0, wv.y, acc[0][1]);
    acc[0][2] = fmaf(h0, wv.z, acc[0][2]);
    acc[0][3] = fmaf(h0, wv.w, acc[0][3]);
    acc[1][0] = fmaf(h1, wv.x, acc[1][0]);
    acc[1][1] = fmaf(h1, wv.y, acc[1][1]);
    acc[1][2] = fmaf(h1, wv.z, acc[1][2]);
    acc[1][3] = fmaf(h1, wv.w, acc[1][3]);
    acc[2][0] = fmaf(h2, wv.x, acc[2][0]);
    acc[2][1] = fmaf(h2, wv.y, acc[2][1]);
    acc[2][2] = fmaf(h2, wv.z, acc[2][2]);
    acc[2][3] = fmaf(h2, wv.w, acc[2][3]);
    acc[3][0] = fmaf(h3, wv.x, acc[3][0]);
    acc[3][1] = fmaf(h3, wv.y, acc[3][1]);
    acc[3][2] = fmaf(h3, wv.z, acc[3][2]);
    acc[3][3] = fmaf(h3, wv.w, acc[3][3]);
  }

  float4 bv = make_float4(0.f, 0.f, 0.f, 0.f);
  if (fuse) bv = *reinterpret_cast<const float4*>(bias + c0);
#pragma unroll
  for (int i = 0; i < 4; ++i) {
    long long row = (long long)row0 + r0 + i;
    if (row >= n) break;
    float4 o = make_float4(acc[i][0], acc[i][1], acc[i][2], acc[i][3]);
    if (fuse) {
      o.x = fmaxf(o.x + bv.x, 0.f);
      o.y = fmaxf(o.y + bv.y, 0.f);
      o.z = fmaxf(o.z + bv.z, 0.f);
      o.w = fmaxf(o.w + bv.w, 0.f);
    }
    if (dinv) {
      float dv = dinv[row];
      o.x *= dv; o.y *= dv; o.z *= dv; o.w *= dv;
    }
    *reinterpret_cast<float4*>(T + (size_t)row * DD + c0) = o;
  }
}

// ---- CSR aggregation: out[d,:] = dinv[d] * sum_{c in N(d)} T'[c,:] + b -----
__global__ __launch_bounds__(256) void aggregate_kernel(
    const float* __restrict__ T, const int* __restrict__ offs,
    const int* __restrict__ col, const float* __restrict__ dinv,
    const float* __restrict__ bias, float* __restrict__ out,
    int n, int relu) {
  int gid = blockIdx.x * blockDim.x + threadIdx.x;
  int wid = gid >> 6;
  int lane = threadIdx.x & 63;
  if (wid >= n) return;
  int j0 = offs[wid], j1 = offs[wid + 1];
  float acc = 0.f;
  int j = j0;
  for (; j + 4 <= j1; j += 4) {
    int c0 = col[j], c1 = col[j + 1], c2 = col[j + 2], c3 = col[j + 3];
    float f0 = T[(size_t)c0 * DD + lane];
    float f1 = T[(size_t)c1 * DD + lane];
    float f2 = T[(size_t)c2 * DD + lane];
    float f3 = T[(size_t)c3 * DD + lane];
    acc += f0 + f1 + f2 + f3;
  }
  for (; j < j1; ++j)
    acc += T[(size_t)col[j] * DD + lane];
  acc = fmaf(acc, dinv[wid], bias[lane]);
  if (relu) acc = fmaxf(acc, 0.f);
  out[(size_t)wid * DD + lane] = acc;
}

// ---------------------------------------------------------------------------
extern "C" void kernel_launch(void* const* d_in, const int* in_sizes, int n_in,
                              void* d_out, int out_size, void* d_ws, size_t ws_size,
                              hipStream_t stream) {
  const float* x   = (const float*)d_in[0];
  const void*  eix = d_in[1];
  const float* Win = (const float*)d_in[2];
  const float* bin = (const float*)d_in[3];
  const float* W1  = (const float*)d_in[4];
  const float* b1  = (const float*)d_in[5];
  const float* W2  = (const float*)d_in[6];
  const float* b2  = (const float*)d_in[7];
  const float* W3  = (const float*)d_in[8];
  const float* b3  = (const float*)d_in[9];

  int n = in_sizes[0] / DD;
  int E = in_sizes[1] / 2;
  int M = E + n;
  int chunk = (n + NB - 1) / NB;    // local-dst fits 16 bits for n <= 65536

  char* w = (char*)d_ws;
  auto carve = [&](size_t bytes) {
    char* p = w;
    w += (bytes + 255) & ~(size_t)255;
    return p;
  };
  int*          flag       = (int*)carve(4);
  int*          histPB     = (int*)carve((size_t)GB * NB * 4);
  int*          base_bb    = (int*)carve((size_t)GB * NB * 4);
  int*          bucketBase = (int*)carve((size_t)(NB + 1) * 4);
  int*          csrBase    = (int*)carve((size_t)NB * 4);
  int*          offs       = (int*)carve((size_t)(n + 1) * 4);
  float*        dinv       = (float*)carve((size_t)n * 4);
  unsigned int* rec        = (unsigned int*)carve((size_t)E * 4);
  int*          col        = (int*)carve((size_t)M * 4);
  float*        hbuf       = (float*)carve((size_t)n * DD * 4);
  float*        tbuf       = (float*)carve((size_t)n * DD * 4);

  detect_i64_kernel<<<1, 64, 0, stream>>>((const unsigned int*)eix, E, flag);
  histA_kernel<<<GB, 256, 0, stream>>>(eix, E, chunk, histPB, flag);
  scanB_kernel<<<1, NB, 0, stream>>>(histPB, base_bb, bucketBase, csrBase,
                                     offs, n, E, chunk);
  passB_kernel<<<GB, 256, 0, stream>>>(eix, E, chunk, base_bb, rec, flag);
  passC_kernel<<<NB, 256, 0, stream>>>(rec, bucketBase, csrBase, offs, dinv,
                                       col, n, chunk);

  int gemm_grid = (n + 63) / 64;
  int agg_grid  = (n * 64 + 255) / 256;

  // layer 0: h = relu(x @ W_in + b_in)      (no dinv scale)
  gemm_kernel<<<gemm_grid, 256, 0, stream>>>(x, Win, bin, nullptr, hbuf, n, 1);

  // conv1: h = relu(dinv*agg(dinv*(h @ W1)) + b1)
  gemm_kernel<<<gemm_grid, 256, 0, stream>>>(hbuf, W1, nullptr, dinv, tbuf, n, 0);
  aggregate_kernel<<<agg_grid, 256, 0, stream>>>(tbuf, offs, col, dinv, b1, hbuf, n, 1);

  // conv2
  gemm_kernel<<<gemm_grid, 256, 0, stream>>>(hbuf, W2, nullptr, dinv, tbuf, n, 0);
  aggregate_kernel<<<agg_grid, 256, 0, stream>>>(tbuf, offs, col, dinv, b2, hbuf, n, 1);

  // conv3 (no relu)
  gemm_kernel<<<gemm_grid, 256, 0, stream>>>(hbuf, W3, nullptr, dinv, tbuf, n, 0);
  aggregate_kernel<<<agg_grid, 256, 0, stream>>>(tbuf, offs, col, dinv, b3, (float*)d_out, n, 0);
}

// Round 7
// 320.066 us; speedup vs baseline: 1.5654x; 1.1501x over previous
//
#include <hip/hip_runtime.h>
#include <hip/hip_fp16.h>

#define DD 64
#define NB 256          // buckets (one per passC block); requires n <= 65536
#define GB 128          // blocks for histA/passB

// ---------------------------------------------------------------------------
// Inline int64-vs-int32 detection: first 128 odd u32 words all zero <=> int64.
__device__ __forceinline__ int detect_is64(const unsigned int* p, int E,
                                           int tid, int* sflag) {
  if (tid == 0) *sflag = 1;
  __syncthreads();
  int lim = E < 128 ? E : 128;
  if (tid < lim && p[2 * tid + 1] != 0u) *sflag = 0;
  __syncthreads();
  return *sflag;
}

// ---- histA: per-(block,bucket) histogram of dst ---------------------------
__global__ __launch_bounds__(256) void histA_kernel(
    const void* __restrict__ eidx, int E, int chunk,
    int* __restrict__ histPB) {
  __shared__ int h[NB];
  __shared__ int sflag;
  int tid = threadIdx.x;
  int is64 = detect_is64((const unsigned int*)eidx, E, tid, &sflag);
  h[tid] = 0;
  __syncthreads();
  int seg = (E + GB - 1) / GB;
  int e0 = blockIdx.x * seg;
  int e1 = min(e0 + seg, E);
  for (int e = e0 + tid; e < e1; e += 256) {
    int d;
    if (is64) d = (int)((const long long*)eidx)[e + E];
    else      d = ((const int*)eidx)[e + E];
    atomicAdd(&h[d / chunk], 1);
  }
  __syncthreads();
  histPB[blockIdx.x * NB + tid] = h[tid];
}

// ---- scanB1: per-bucket scan over the GB block counts ---------------------
__global__ __launch_bounds__(GB) void scanB1_kernel(
    const int* __restrict__ histPB, int* __restrict__ localpre,
    int* __restrict__ tot) {
  __shared__ int s[GB];
  int b = blockIdx.x;        // bucket
  int t = threadIdx.x;       // source block
  int v = histPB[t * NB + b];
  s[t] = v;
  __syncthreads();
  for (int off = 1; off < GB; off <<= 1) {
    int tv = (t >= off) ? s[t - off] : 0;
    __syncthreads();
    s[t] += tv;
    __syncthreads();
  }
  localpre[b * GB + t] = s[t] - v;   // exclusive prefix within bucket
  if (t == GB - 1) tot[b] = s[t];
}

// ---- scanB2: scan bucket totals -> bucketBase, csrBase, offs[n] -----------
__global__ __launch_bounds__(NB) void scanB2_kernel(
    const int* __restrict__ tot, int* __restrict__ bucketBase,
    int* __restrict__ csrBase, int* __restrict__ offs, int n, int chunk) {
  __shared__ int sc[NB];
  int b = threadIdx.x;
  int v = tot[b];
  sc[b] = v;
  __syncthreads();
  for (int off = 1; off < NB; off <<= 1) {
    int t = (b >= off) ? sc[b - off] : 0;
    __syncthreads();
    sc[b] += t;
    __syncthreads();
  }
  int excl = sc[b] - v;
  bucketBase[b] = excl;
  if (b == NB - 1) {
    bucketBase[NB] = excl + v;       // == E
    offs[n] = excl + v + n;          // == E + n
  }
  int dpre = b * chunk; if (dpre > n) dpre = n;
  csrBase[b] = excl + dpre;
}

// ---- passB: bucketed scatter of packed records (src<<16 | local_dst) ------
__global__ __launch_bounds__(256) void passB_kernel(
    const void* __restrict__ eidx, int E, int chunk,
    const int* __restrict__ bucketBase, const int* __restrict__ localpre,
    unsigned int* __restrict__ rec) {
  __shared__ int cur[NB];
  __shared__ int sflag;
  int tid = threadIdx.x;
  int is64 = detect_is64((const unsigned int*)eidx, E, tid, &sflag);
  cur[tid] = bucketBase[tid] + localpre[tid * GB + blockIdx.x];
  __syncthreads();
  int seg = (E + GB - 1) / GB;
  int e0 = blockIdx.x * seg;
  int e1 = min(e0 + seg, E);
  for (int e = e0 + tid; e < e1; e += 256) {
    int s, d;
    if (is64) {
      const long long* p = (const long long*)eidx;
      s = (int)p[e];
      d = (int)p[e + E];
    } else {
      const int* p = (const int*)eidx;
      s = p[e];
      d = p[e + E];
    }
    int b = d / chunk;
    int ld = d - b * chunk;
    int pos = atomicAdd(&cur[b], 1);
    rec[pos] = ((unsigned int)s << 16) | (unsigned int)ld;
  }
}

// ---- passC: per-bucket CSR finalize (offs, dinv, col) ---------------------
__global__ __launch_bounds__(256) void passC_kernel(
    const unsigned int* __restrict__ rec, const int* __restrict__ bucketBase,
    const int* __restrict__ csrBase, int* __restrict__ offs,
    float* __restrict__ dinv, int* __restrict__ col, int n, int chunk) {
  int b = blockIdx.x;
  int tid = threadIdx.x;
  int d0 = b * chunk;
  if (d0 >= n) return;
  int nd = min(chunk, n - d0);
  int jb0 = bucketBase[b], jb1 = bucketBase[b + 1];
  int cb = csrBase[b];

  __shared__ int hist[NB];
  __shared__ int sc[NB];
  __shared__ int cursor[NB];
  hist[tid] = (tid < nd) ? 1 : 0;   // self-loop seed
  __syncthreads();
  for (int j = jb0 + tid; j < jb1; j += 256)
    atomicAdd(&hist[rec[j] & 0xFFFFu], 1);
  __syncthreads();
  int deg = hist[tid];
  sc[tid] = deg;
  __syncthreads();
  for (int off = 1; off < NB; off <<= 1) {
    int t = (tid >= off) ? sc[tid - off] : 0;
    __syncthreads();
    sc[tid] += t;
    __syncthreads();
  }
  int loc = sc[tid] - deg;          // exclusive prefix
  if (tid < nd) {
    offs[d0 + tid] = cb + loc;
    dinv[d0 + tid] = rsqrtf((float)deg);
    col[cb + loc] = d0 + tid;       // self-loop first
  }
  cursor[tid] = loc + 1;
  __syncthreads();
  for (int j = jb0 + tid; j < jb1; j += 256) {
    unsigned int r = rec[j];
    int ld = (int)(r & 0xFFFFu);
    int s  = (int)(r >> 16);
    int p = atomicAdd(&cursor[ld], 1);
    col[cb + p] = s;
  }
}

// ---- dense GEMM: T = H @ W; epilogue: bias+relu (fuse) / dinv-scale -------
// Writes fp32 to T32 if T16==nullptr, else fp16 to T16.
__global__ __launch_bounds__(256) void gemm_kernel(
    const float* __restrict__ H, const float* __restrict__ W,
    const float* __restrict__ bias, const float* __restrict__ dinv,
    float* __restrict__ T32, __half* __restrict__ T16, int n, int fuse) {
  __shared__ float Ws[64][68];
  __shared__ float Hs[64][68];
  int tid = threadIdx.x;
  int row0 = blockIdx.x * 64;

  for (int i = tid; i < 1024; i += 256) {
    int r = i >> 4, c = (i & 15) << 2;
    float4 wv = ((const float4*)W)[i];
    *reinterpret_cast<float4*>(&Ws[r][c]) = wv;
    float4 hv = make_float4(0.f, 0.f, 0.f, 0.f);
    if (row0 + r < n)
      hv = *reinterpret_cast<const float4*>(H + (size_t)(row0 + r) * DD + c);
    *reinterpret_cast<float4*>(&Hs[r][c]) = hv;
  }
  __syncthreads();

  int tr = tid >> 4, tc = tid & 15;
  int r0 = tr << 2, c0 = tc << 2;

  float acc[4][4];
#pragma unroll
  for (int i = 0; i < 4; ++i)
#pragma unroll
    for (int j = 0; j < 4; ++j) acc[i][j] = 0.f;

#pragma unroll
  for (int k = 0; k < 64; ++k) {
    float h0 = Hs[r0 + 0][k];
    float h1 = Hs[r0 + 1][k];
    float h2 = Hs[r0 + 2][k];
    float h3 = Hs[r0 + 3][k];
    float4 wv = *reinterpret_cast<const float4*>(&Ws[k][c0]);
    acc[0][0] = fmaf(h0, wv.x, acc[0][0]);
    acc[0][1] = fmaf(h0, wv.y, acc[0][1]);
    acc[0][2] = fmaf(h0, wv.z, acc[0][2]);
    acc[0][3] = fmaf(h0, wv.w, acc[0][3]);
    acc[1][0] = fmaf(h1, wv.x, acc[1][0]);
    acc[1][1] = fmaf(h1, wv.y, acc[1][1]);
    acc[1][2] = fmaf(h1, wv.z, acc[1][2]);
    acc[1][3] = fmaf(h1, wv.w, acc[1][3]);
    acc[2][0] = fmaf(h2, wv.x, acc[2][0]);
    acc[2][1] = fmaf(h2, wv.y, acc[2][1]);
    acc[2][2] = fmaf(h2, wv.z, acc[2][2]);
    acc[2][3] = fmaf(h2, wv.w, acc[2][3]);
    acc[3][0] = fmaf(h3, wv.x, acc[3][0]);
    acc[3][1] = fmaf(h3, wv.y, acc[3][1]);
    acc[3][2] = fmaf(h3, wv.z, acc[3][2]);
    acc[3][3] = fmaf(h3, wv.w, acc[3][3]);
  }

  float4 bv = make_float4(0.f, 0.f, 0.f, 0.f);
  if (fuse) bv = *reinterpret_cast<const float4*>(bias + c0);
#pragma unroll
  for (int i = 0; i < 4; ++i) {
    long long row = (long long)row0 + r0 + i;
    if (row >= n) break;
    float4 o = make_float4(acc[i][0], acc[i][1], acc[i][2], acc[i][3]);
    if (fuse) {
      o.x = fmaxf(o.x + bv.x, 0.f);
      o.y = fmaxf(o.y + bv.y, 0.f);
      o.z = fmaxf(o.z + bv.z, 0.f);
      o.w = fmaxf(o.w + bv.w, 0.f);
    }
    if (dinv) {
      float dv = dinv[row];
      o.x *= dv; o.y *= dv; o.z *= dv; o.w *= dv;
    }
    if (T16) {
      __half2 p01 = __floats2half2_rn(o.x, o.y);
      __half2 p23 = __floats2half2_rn(o.z, o.w);
      uint2 u;
      u.x = *reinterpret_cast<unsigned int*>(&p01);
      u.y = *reinterpret_cast<unsigned int*>(&p23);
      *reinterpret_cast<uint2*>(T16 + (size_t)row * DD + c0) = u;
    } else {
      *reinterpret_cast<float4*>(T32 + (size_t)row * DD + c0) = o;
    }
  }
}

// ---- CSR aggregation: out[d,:] = dinv[d] * sum_{c in N(d)} T16[c,:] + b ---
// one wave (64 lanes) per node, lane = feature dim. fp16 gather, fp32 accum.
__global__ __launch_bounds__(256) void aggregate_kernel(
    const __half* __restrict__ T, const int* __restrict__ offs,
    const int* __restrict__ col, const float* __restrict__ dinv,
    const float* __restrict__ bias, float* __restrict__ out,
    int n, int relu) {
  int gid = blockIdx.x * blockDim.x + threadIdx.x;
  int wid = gid >> 6;
  int lane = threadIdx.x & 63;
  if (wid >= n) return;
  int j0 = offs[wid], j1 = offs[wid + 1];
  float acc = 0.f;
  int j = j0;
  for (; j + 8 <= j1; j += 8) {
    int c0 = col[j + 0], c1 = col[j + 1], c2 = col[j + 2], c3 = col[j + 3];
    int c4 = col[j + 4], c5 = col[j + 5], c6 = col[j + 6], c7 = col[j + 7];
    float f0 = __half2float(T[(size_t)c0 * DD + lane]);
    float f1 = __half2float(T[(size_t)c1 * DD + lane]);
    float f2 = __half2float(T[(size_t)c2 * DD + lane]);
    float f3 = __half2float(T[(size_t)c3 * DD + lane]);
    float f4 = __half2float(T[(size_t)c4 * DD + lane]);
    float f5 = __half2float(T[(size_t)c5 * DD + lane]);
    float f6 = __half2float(T[(size_t)c6 * DD + lane]);
    float f7 = __half2float(T[(size_t)c7 * DD + lane]);
    acc += ((f0 + f1) + (f2 + f3)) + ((f4 + f5) + (f6 + f7));
  }
  for (; j < j1; ++j)
    acc += __half2float(T[(size_t)col[j] * DD + lane]);
  acc = fmaf(acc, dinv[wid], bias[lane]);
  if (relu) acc = fmaxf(acc, 0.f);
  out[(size_t)wid * DD + lane] = acc;
}

// ---------------------------------------------------------------------------
extern "C" void kernel_launch(void* const* d_in, const int* in_sizes, int n_in,
                              void* d_out, int out_size, void* d_ws, size_t ws_size,
                              hipStream_t stream) {
  const float* x   = (const float*)d_in[0];
  const void*  eix = d_in[1];
  const float* Win = (const float*)d_in[2];
  const float* bin = (const float*)d_in[3];
  const float* W1  = (const float*)d_in[4];
  const float* b1  = (const float*)d_in[5];
  const float* W2  = (const float*)d_in[6];
  const float* b2  = (const float*)d_in[7];
  const float* W3  = (const float*)d_in[8];
  const float* b3  = (const float*)d_in[9];

  int n = in_sizes[0] / DD;
  int E = in_sizes[1] / 2;
  int M = E + n;
  int chunk = (n + NB - 1) / NB;    // local-dst fits 16 bits for n <= 65536

  char* w = (char*)d_ws;
  auto carve = [&](size_t bytes) {
    char* p = w;
    w += (bytes + 255) & ~(size_t)255;
    return p;
  };
  int*          histPB     = (int*)carve((size_t)GB * NB * 4);
  int*          localpre   = (int*)carve((size_t)NB * GB * 4);
  int*          tot        = (int*)carve((size_t)NB * 4);
  int*          bucketBase = (int*)carve((size_t)(NB + 1) * 4);
  int*          csrBase    = (int*)carve((size_t)NB * 4);
  int*          offs       = (int*)carve((size_t)(n + 1) * 4);
  float*        dinv       = (float*)carve((size_t)n * 4);
  unsigned int* rec        = (unsigned int*)carve((size_t)E * 4);
  int*          col        = (int*)carve((size_t)M * 4);
  float*        hbuf       = (float*)carve((size_t)n * DD * 4);
  __half*       t16        = (__half*)carve((size_t)n * DD * 2);

  histA_kernel<<<GB, 256, 0, stream>>>(eix, E, chunk, histPB);
  scanB1_kernel<<<NB, GB, 0, stream>>>(histPB, localpre, tot);
  scanB2_kernel<<<1, NB, 0, stream>>>(tot, bucketBase, csrBase, offs, n, chunk);
  passB_kernel<<<GB, 256, 0, stream>>>(eix, E, chunk, bucketBase, localpre, rec);
  passC_kernel<<<NB, 256, 0, stream>>>(rec, bucketBase, csrBase, offs, dinv,
                                       col, n, chunk);

  int gemm_grid = (n + 63) / 64;
  int agg_grid  = (n * 64 + 255) / 256;

  // layer 0: h = relu(x @ W_in + b_in)      (fp32 out, no dinv scale)
  gemm_kernel<<<gemm_grid, 256, 0, stream>>>(x, Win, bin, nullptr, hbuf, nullptr, n, 1);

  // conv1: h = relu(dinv*agg(fp16(dinv*(h @ W1))) + b1)
  gemm_kernel<<<gemm_grid, 256, 0, stream>>>(hbuf, W1, nullptr, dinv, nullptr, t16, n, 0);
  aggregate_kernel<<<agg_grid, 256, 0, stream>>>(t16, offs, col, dinv, b1, hbuf, n, 1);

  // conv2
  gemm_kernel<<<gemm_grid, 256, 0, stream>>>(hbuf, W2, nullptr, dinv, nullptr, t16, n, 0);
  aggregate_kernel<<<agg_grid, 256, 0, stream>>>(t16, offs, col, dinv, b2, hbuf, n, 1);

  // conv3 (no relu)
  gemm_kernel<<<gemm_grid, 256, 0, stream>>>(hbuf, W3, nullptr, dinv, nullptr, t16, n, 0);
  aggregate_kernel<<<agg_grid, 256, 0, stream>>>(t16, offs, col, dinv, b3, (float*)d_out, n, 0);
}

// Round 8
// 273.097 us; speedup vs baseline: 1.8347x; 1.1720x over previous
//
#include <hip/hip_runtime.h>
#include <hip/hip_fp16.h>

#define DD 64
#define NB 256          // buckets (one per passC block); requires n <= 65536
#define GB 128          // blocks for histA/passB

// ---------------------------------------------------------------------------
// Inline int64-vs-int32 detection: first 128 odd u32 words all zero <=> int64.
__device__ __forceinline__ int detect_is64(const unsigned int* p, int E,
                                           int tid, int* sflag) {
  if (tid == 0) *sflag = 1;
  __syncthreads();
  int lim = E < 128 ? E : 128;
  if (tid < lim && p[2 * tid + 1] != 0u) *sflag = 0;
  __syncthreads();
  return *sflag;
}

// ---- histA: per-(block,bucket) histogram of dst ---------------------------
__global__ __launch_bounds__(256) void histA_kernel(
    const void* __restrict__ eidx, int E, int chunk,
    int* __restrict__ histPB) {
  __shared__ int h[NB];
  __shared__ int sflag;
  int tid = threadIdx.x;
  int is64 = detect_is64((const unsigned int*)eidx, E, tid, &sflag);
  h[tid] = 0;
  __syncthreads();
  int seg = (E + GB - 1) / GB;
  int e0 = blockIdx.x * seg;
  int e1 = min(e0 + seg, E);
  for (int e = e0 + tid; e < e1; e += 256) {
    int d;
    if (is64) d = (int)((const long long*)eidx)[e + E];
    else      d = ((const int*)eidx)[e + E];
    atomicAdd(&h[d / chunk], 1);
  }
  __syncthreads();
  histPB[blockIdx.x * NB + tid] = h[tid];
}

// ---- scanB1: per-bucket scan over the GB block counts ---------------------
__global__ __launch_bounds__(GB) void scanB1_kernel(
    const int* __restrict__ histPB, int* __restrict__ localpre,
    int* __restrict__ tot) {
  __shared__ int s[GB];
  int b = blockIdx.x;        // bucket
  int t = threadIdx.x;       // source block
  int v = histPB[t * NB + b];
  s[t] = v;
  __syncthreads();
  for (int off = 1; off < GB; off <<= 1) {
    int tv = (t >= off) ? s[t - off] : 0;
    __syncthreads();
    s[t] += tv;
    __syncthreads();
  }
  localpre[b * GB + t] = s[t] - v;   // exclusive prefix within bucket
  if (t == GB - 1) tot[b] = s[t];
}

// ---- scanB2: scan bucket totals -> bucketBase, csrBase, offs[n] -----------
__global__ __launch_bounds__(NB) void scanB2_kernel(
    const int* __restrict__ tot, int* __restrict__ bucketBase,
    int* __restrict__ csrBase, int* __restrict__ offs, int n, int chunk) {
  __shared__ int sc[NB];
  int b = threadIdx.x;
  int v = tot[b];
  sc[b] = v;
  __syncthreads();
  for (int off = 1; off < NB; off <<= 1) {
    int t = (b >= off) ? sc[b - off] : 0;
    __syncthreads();
    sc[b] += t;
    __syncthreads();
  }
  int excl = sc[b] - v;
  bucketBase[b] = excl;
  if (b == NB - 1) {
    bucketBase[NB] = excl + v;       // == E
    offs[n] = excl + v + n;          // == E + n
  }
  int dpre = b * chunk; if (dpre > n) dpre = n;
  csrBase[b] = excl + dpre;
}

// ---- passB: bucketed scatter of packed records (src<<16 | local_dst) ------
__global__ __launch_bounds__(256) void passB_kernel(
    const void* __restrict__ eidx, int E, int chunk,
    const int* __restrict__ bucketBase, const int* __restrict__ localpre,
    unsigned int* __restrict__ rec) {
  __shared__ int cur[NB];
  __shared__ int sflag;
  int tid = threadIdx.x;
  int is64 = detect_is64((const unsigned int*)eidx, E, tid, &sflag);
  cur[tid] = bucketBase[tid] + localpre[tid * GB + blockIdx.x];
  __syncthreads();
  int seg = (E + GB - 1) / GB;
  int e0 = blockIdx.x * seg;
  int e1 = min(e0 + seg, E);
  for (int e = e0 + tid; e < e1; e += 256) {
    int s, d;
    if (is64) {
      const long long* p = (const long long*)eidx;
      s = (int)p[e];
      d = (int)p[e + E];
    } else {
      const int* p = (const int*)eidx;
      s = p[e];
      d = p[e + E];
    }
    int b = d / chunk;
    int ld = d - b * chunk;
    int pos = atomicAdd(&cur[b], 1);
    rec[pos] = ((unsigned int)s << 16) | (unsigned int)ld;
  }
}

// ---- passC: per-bucket CSR finalize (offs, dinv, col) ---------------------
__global__ __launch_bounds__(256) void passC_kernel(
    const unsigned int* __restrict__ rec, const int* __restrict__ bucketBase,
    const int* __restrict__ csrBase, int* __restrict__ offs,
    float* __restrict__ dinv, int* __restrict__ col, int n, int chunk) {
  int b = blockIdx.x;
  int tid = threadIdx.x;
  int d0 = b * chunk;
  if (d0 >= n) return;
  int nd = min(chunk, n - d0);
  int jb0 = bucketBase[b], jb1 = bucketBase[b + 1];
  int cb = csrBase[b];

  __shared__ int hist[NB];
  __shared__ int sc[NB];
  __shared__ int cursor[NB];
  hist[tid] = (tid < nd) ? 1 : 0;   // self-loop seed
  __syncthreads();
  for (int j = jb0 + tid; j < jb1; j += 256)
    atomicAdd(&hist[rec[j] & 0xFFFFu], 1);
  __syncthreads();
  int deg = hist[tid];
  sc[tid] = deg;
  __syncthreads();
  for (int off = 1; off < NB; off <<= 1) {
    int t = (tid >= off) ? sc[tid - off] : 0;
    __syncthreads();
    sc[tid] += t;
    __syncthreads();
  }
  int loc = sc[tid] - deg;          // exclusive prefix
  if (tid < nd) {
    offs[d0 + tid] = cb + loc;
    dinv[d0 + tid] = rsqrtf((float)deg);
    col[cb + loc] = d0 + tid;       // self-loop first
  }
  cursor[tid] = loc + 1;
  __syncthreads();
  for (int j = jb0 + tid; j < jb1; j += 256) {
    unsigned int r = rec[j];
    int ld = (int)(r & 0xFFFFu);
    int s  = (int)(r >> 16);
    int p = atomicAdd(&cursor[ld], 1);
    col[cb + p] = s;
  }
}

// ---- dense GEMM: T = H @ W; epilogue: bias+relu (fuse) / dinv-scale -------
// Writes fp32 to T32 if T16==nullptr, else fp16 to T16.
__global__ __launch_bounds__(256) void gemm_kernel(
    const float* __restrict__ H, const float* __restrict__ W,
    const float* __restrict__ bias, const float* __restrict__ dinv,
    float* __restrict__ T32, __half* __restrict__ T16, int n, int fuse) {
  __shared__ float Ws[64][68];
  __shared__ float Hs[64][68];
  int tid = threadIdx.x;
  int row0 = blockIdx.x * 64;

  for (int i = tid; i < 1024; i += 256) {
    int r = i >> 4, c = (i & 15) << 2;
    float4 wv = ((const float4*)W)[i];
    *reinterpret_cast<float4*>(&Ws[r][c]) = wv;
    float4 hv = make_float4(0.f, 0.f, 0.f, 0.f);
    if (row0 + r < n)
      hv = *reinterpret_cast<const float4*>(H + (size_t)(row0 + r) * DD + c);
    *reinterpret_cast<float4*>(&Hs[r][c]) = hv;
  }
  __syncthreads();

  int tr = tid >> 4, tc = tid & 15;
  int r0 = tr << 2, c0 = tc << 2;

  float acc[4][4];
#pragma unroll
  for (int i = 0; i < 4; ++i)
#pragma unroll
    for (int j = 0; j < 4; ++j) acc[i][j] = 0.f;

#pragma unroll
  for (int k = 0; k < 64; ++k) {
    float h0 = Hs[r0 + 0][k];
    float h1 = Hs[r0 + 1][k];
    float h2 = Hs[r0 + 2][k];
    float h3 = Hs[r0 + 3][k];
    float4 wv = *reinterpret_cast<const float4*>(&Ws[k][c0]);
    acc[0][0] = fmaf(h0, wv.x, acc[0][0]);
    acc[0][1] = fmaf(h0, wv.y, acc[0][1]);
    acc[0][2] = fmaf(h0, wv.z, acc[0][2]);
    acc[0][3] = fmaf(h0, wv.w, acc[0][3]);
    acc[1][0] = fmaf(h1, wv.x, acc[1][0]);
    acc[1][1] = fmaf(h1, wv.y, acc[1][1]);
    acc[1][2] = fmaf(h1, wv.z, acc[1][2]);
    acc[1][3] = fmaf(h1, wv.w, acc[1][3]);
    acc[2][0] = fmaf(h2, wv.x, acc[2][0]);
    acc[2][1] = fmaf(h2, wv.y, acc[2][1]);
    acc[2][2] = fmaf(h2, wv.z, acc[2][2]);
    acc[2][3] = fmaf(h2, wv.w, acc[2][3]);
    acc[3][0] = fmaf(h3, wv.x, acc[3][0]);
    acc[3][1] = fmaf(h3, wv.y, acc[3][1]);
    acc[3][2] = fmaf(h3, wv.z, acc[3][2]);
    acc[3][3] = fmaf(h3, wv.w, acc[3][3]);
  }

  float4 bv = make_float4(0.f, 0.f, 0.f, 0.f);
  if (fuse) bv = *reinterpret_cast<const float4*>(bias + c0);
#pragma unroll
  for (int i = 0; i < 4; ++i) {
    long long row = (long long)row0 + r0 + i;
    if (row >= n) break;
    float4 o = make_float4(acc[i][0], acc[i][1], acc[i][2], acc[i][3]);
    if (fuse) {
      o.x = fmaxf(o.x + bv.x, 0.f);
      o.y = fmaxf(o.y + bv.y, 0.f);
      o.z = fmaxf(o.z + bv.z, 0.f);
      o.w = fmaxf(o.w + bv.w, 0.f);
    }
    if (dinv) {
      float dv = dinv[row];
      o.x *= dv; o.y *= dv; o.z *= dv; o.w *= dv;
    }
    if (T16) {
      __half2 p01 = __floats2half2_rn(o.x, o.y);
      __half2 p23 = __floats2half2_rn(o.z, o.w);
      uint2 u;
      u.x = *reinterpret_cast<unsigned int*>(&p01);
      u.y = *reinterpret_cast<unsigned int*>(&p23);
      *reinterpret_cast<uint2*>(T16 + (size_t)row * DD + c0) = u;
    } else {
      *reinterpret_cast<float4*>(T32 + (size_t)row * DD + c0) = o;
    }
  }
}

// ---- CSR aggregation: out[d,:] = dinv[d] * sum_{c in N(d)} T16[c,:] + b ---
// one wave per node; lane = (row-group g = lane>>3, dim-slice s = lane&7).
// Per iteration the wave gathers 8 neighbor rows; each lane loads 16 B
// (8 halves) of its row. Epilogue: shfl_xor reduce over g, lanes g==0 write.
__device__ __forceinline__ void acc8(float* acc, uint4 u) {
  __half2 h0 = *reinterpret_cast<__half2*>(&u.x);
  __half2 h1 = *reinterpret_cast<__half2*>(&u.y);
  __half2 h2 = *reinterpret_cast<__half2*>(&u.z);
  __half2 h3 = *reinterpret_cast<__half2*>(&u.w);
  float2 f0 = __half22float2(h0);
  float2 f1 = __half22float2(h1);
  float2 f2 = __half22float2(h2);
  float2 f3 = __half22float2(h3);
  acc[0] += f0.x; acc[1] += f0.y;
  acc[2] += f1.x; acc[3] += f1.y;
  acc[4] += f2.x; acc[5] += f2.y;
  acc[6] += f3.x; acc[7] += f3.y;
}

__global__ __launch_bounds__(256) void aggregate_kernel(
    const __half* __restrict__ T, const int* __restrict__ offs,
    const int* __restrict__ col, const float* __restrict__ dinv,
    const float* __restrict__ bias, float* __restrict__ out,
    int n, int relu) {
  int gid = blockIdx.x * blockDim.x + threadIdx.x;
  int wid = gid >> 6;
  if (wid >= n) return;
  int lane = threadIdx.x & 63;
  int g = lane >> 3;          // row group 0..7
  int s = lane & 7;           // dim slice: dims 8s..8s+7
  int j0 = offs[wid], j1 = offs[wid + 1];

  float acc[8];
#pragma unroll
  for (int k = 0; k < 8; ++k) acc[k] = 0.f;

  int j = j0 + g;
  // dual-issue: two row-groups (16 rows) in flight
  for (; j + 8 < j1; j += 16) {
    int cA = col[j];
    int cB = col[j + 8];
    uint4 uA = *reinterpret_cast<const uint4*>(T + (size_t)cA * DD + s * 8);
    uint4 uB = *reinterpret_cast<const uint4*>(T + (size_t)cB * DD + s * 8);
    acc8(acc, uA);
    acc8(acc, uB);
  }
  if (j < j1) {
    int cA = col[j];
    uint4 uA = *reinterpret_cast<const uint4*>(T + (size_t)cA * DD + s * 8);
    acc8(acc, uA);
  }

  // reduce over g (lane bits 3,4,5)
#pragma unroll
  for (int m = 8; m <= 32; m <<= 1) {
#pragma unroll
    for (int k = 0; k < 8; ++k)
      acc[k] += __shfl_xor(acc[k], m, 64);
  }

  if (g == 0) {
    float dv = dinv[wid];
    const float4* bp = reinterpret_cast<const float4*>(bias + s * 8);
    float4 b0 = bp[0], b1 = bp[1];
    float4 o0, o1;
    o0.x = fmaf(acc[0], dv, b0.x);
    o0.y = fmaf(acc[1], dv, b0.y);
    o0.z = fmaf(acc[2], dv, b0.z);
    o0.w = fmaf(acc[3], dv, b0.w);
    o1.x = fmaf(acc[4], dv, b1.x);
    o1.y = fmaf(acc[5], dv, b1.y);
    o1.z = fmaf(acc[6], dv, b1.z);
    o1.w = fmaf(acc[7], dv, b1.w);
    if (relu) {
      o0.x = fmaxf(o0.x, 0.f); o0.y = fmaxf(o0.y, 0.f);
      o0.z = fmaxf(o0.z, 0.f); o0.w = fmaxf(o0.w, 0.f);
      o1.x = fmaxf(o1.x, 0.f); o1.y = fmaxf(o1.y, 0.f);
      o1.z = fmaxf(o1.z, 0.f); o1.w = fmaxf(o1.w, 0.f);
    }
    float4* op = reinterpret_cast<float4*>(out + (size_t)wid * DD + s * 8);
    op[0] = o0;
    op[1] = o1;
  }
}

// ---------------------------------------------------------------------------
extern "C" void kernel_launch(void* const* d_in, const int* in_sizes, int n_in,
                              void* d_out, int out_size, void* d_ws, size_t ws_size,
                              hipStream_t stream) {
  const float* x   = (const float*)d_in[0];
  const void*  eix = d_in[1];
  const float* Win = (const float*)d_in[2];
  const float* bin = (const float*)d_in[3];
  const float* W1  = (const float*)d_in[4];
  const float* b1  = (const float*)d_in[5];
  const float* W2  = (const float*)d_in[6];
  const float* b2  = (const float*)d_in[7];
  const float* W3  = (const float*)d_in[8];
  const float* b3  = (const float*)d_in[9];

  int n = in_sizes[0] / DD;
  int E = in_sizes[1] / 2;
  int M = E + n;
  int chunk = (n + NB - 1) / NB;    // local-dst fits 16 bits for n <= 65536

  char* w = (char*)d_ws;
  auto carve = [&](size_t bytes) {
    char* p = w;
    w += (bytes + 255) & ~(size_t)255;
    return p;
  };
  int*          histPB     = (int*)carve((size_t)GB * NB * 4);
  int*          localpre   = (int*)carve((size_t)NB * GB * 4);
  int*          tot        = (int*)carve((size_t)NB * 4);
  int*          bucketBase = (int*)carve((size_t)(NB + 1) * 4);
  int*          csrBase    = (int*)carve((size_t)NB * 4);
  int*          offs       = (int*)carve((size_t)(n + 1) * 4);
  float*        dinv       = (float*)carve((size_t)n * 4);
  unsigned int* rec        = (unsigned int*)carve((size_t)E * 4);
  int*          col        = (int*)carve((size_t)M * 4);
  float*        hbuf       = (float*)carve((size_t)n * DD * 4);
  __half*       t16        = (__half*)carve((size_t)n * DD * 2);

  histA_kernel<<<GB, 256, 0, stream>>>(eix, E, chunk, histPB);
  scanB1_kernel<<<NB, GB, 0, stream>>>(histPB, localpre, tot);
  scanB2_kernel<<<1, NB, 0, stream>>>(tot, bucketBase, csrBase, offs, n, chunk);
  passB_kernel<<<GB, 256, 0, stream>>>(eix, E, chunk, bucketBase, localpre, rec);
  passC_kernel<<<NB, 256, 0, stream>>>(rec, bucketBase, csrBase, offs, dinv,
                                       col, n, chunk);

  int gemm_grid = (n + 63) / 64;
  int agg_grid  = (n * 64 + 255) / 256;

  // layer 0: h = relu(x @ W_in + b_in)      (fp32 out, no dinv scale)
  gemm_kernel<<<gemm_grid, 256, 0, stream>>>(x, Win, bin, nullptr, hbuf, nullptr, n, 1);

  // conv1: h = relu(dinv*agg(fp16(dinv*(h @ W1))) + b1)
  gemm_kernel<<<gemm_grid, 256, 0, stream>>>(hbuf, W1, nullptr, dinv, nullptr, t16, n, 0);
  aggregate_kernel<<<agg_grid, 256, 0, stream>>>(t16, offs, col, dinv, b1, hbuf, n, 1);

  // conv2
  gemm_kernel<<<gemm_grid, 256, 0, stream>>>(hbuf, W2, nullptr, dinv, nullptr, t16, n, 0);
  aggregate_kernel<<<agg_grid, 256, 0, stream>>>(t16, offs, col, dinv, b2, hbuf, n, 1);

  // conv3 (no relu)
  gemm_kernel<<<gemm_grid, 256, 0, stream>>>(hbuf, W3, nullptr, dinv, nullptr, t16, n, 0);
  aggregate_kernel<<<agg_grid, 256, 0, stream>>>(t16, offs, col, dinv, b3, (float*)d_out, n, 0);
}

// Round 9
// 262.700 us; speedup vs baseline: 1.9073x; 1.0396x over previous
//
#include <hip/hip_runtime.h>
#include <hip/hip_fp16.h>

#define DD 64
#define NB 256          // buckets (one per passC block); requires n <= 65536
#define GB 128          // blocks for histA/passB

// ---------------------------------------------------------------------------
// Inline int64-vs-int32 detection: first 128 odd u32 words all zero <=> int64.
__device__ __forceinline__ int detect_is64(const unsigned int* p, int E,
                                           int tid, int* sflag) {
  if (tid == 0) *sflag = 1;
  __syncthreads();
  int lim = E < 128 ? E : 128;
  if (tid < lim && p[2 * tid + 1] != 0u) *sflag = 0;
  __syncthreads();
  return *sflag;
}

// ---- histA: per-(block,bucket) histogram of dst ---------------------------
__global__ __launch_bounds__(256) void histA_kernel(
    const void* __restrict__ eidx, int E, int chunk,
    int* __restrict__ histPB) {
  __shared__ int h[NB];
  __shared__ int sflag;
  int tid = threadIdx.x;
  int is64 = detect_is64((const unsigned int*)eidx, E, tid, &sflag);
  h[tid] = 0;
  __syncthreads();
  int seg = (E + GB - 1) / GB;
  int e0 = blockIdx.x * seg;
  int e1 = min(e0 + seg, E);
  for (int e = e0 + tid; e < e1; e += 256) {
    int d;
    if (is64) d = (int)((const long long*)eidx)[e + E];
    else      d = ((const int*)eidx)[e + E];
    atomicAdd(&h[d / chunk], 1);
  }
  __syncthreads();
  histPB[blockIdx.x * NB + tid] = h[tid];
}

// ---- scanB1: per-bucket scan over the GB block counts ---------------------
__global__ __launch_bounds__(GB) void scanB1_kernel(
    const int* __restrict__ histPB, int* __restrict__ localpre,
    int* __restrict__ tot) {
  __shared__ int s[GB];
  int b = blockIdx.x;        // bucket
  int t = threadIdx.x;       // source block
  int v = histPB[t * NB + b];
  s[t] = v;
  __syncthreads();
  for (int off = 1; off < GB; off <<= 1) {
    int tv = (t >= off) ? s[t - off] : 0;
    __syncthreads();
    s[t] += tv;
    __syncthreads();
  }
  localpre[b * GB + t] = s[t] - v;   // exclusive prefix within bucket
  if (t == GB - 1) tot[b] = s[t];
}

// ---- scanB2: scan bucket totals -> bucketBase, csrBase, offs[n] -----------
__global__ __launch_bounds__(NB) void scanB2_kernel(
    const int* __restrict__ tot, int* __restrict__ bucketBase,
    int* __restrict__ csrBase, int* __restrict__ offs, int n, int chunk) {
  __shared__ int sc[NB];
  int b = threadIdx.x;
  int v = tot[b];
  sc[b] = v;
  __syncthreads();
  for (int off = 1; off < NB; off <<= 1) {
    int t = (b >= off) ? sc[b - off] : 0;
    __syncthreads();
    sc[b] += t;
    __syncthreads();
  }
  int excl = sc[b] - v;
  bucketBase[b] = excl;
  if (b == NB - 1) {
    bucketBase[NB] = excl + v;       // == E
    offs[n] = excl + v + n;          // == E + n
  }
  int dpre = b * chunk; if (dpre > n) dpre = n;
  csrBase[b] = excl + dpre;
}

// ---- passB: bucketed scatter of packed records (src<<16 | local_dst) ------
__global__ __launch_bounds__(256) void passB_kernel(
    const void* __restrict__ eidx, int E, int chunk,
    const int* __restrict__ bucketBase, const int* __restrict__ localpre,
    unsigned int* __restrict__ rec) {
  __shared__ int cur[NB];
  __shared__ int sflag;
  int tid = threadIdx.x;
  int is64 = detect_is64((const unsigned int*)eidx, E, tid, &sflag);
  cur[tid] = bucketBase[tid] + localpre[tid * GB + blockIdx.x];
  __syncthreads();
  int seg = (E + GB - 1) / GB;
  int e0 = blockIdx.x * seg;
  int e1 = min(e0 + seg, E);
  for (int e = e0 + tid; e < e1; e += 256) {
    int s, d;
    if (is64) {
      const long long* p = (const long long*)eidx;
      s = (int)p[e];
      d = (int)p[e + E];
    } else {
      const int* p = (const int*)eidx;
      s = p[e];
      d = p[e + E];
    }
    int b = d / chunk;
    int ld = d - b * chunk;
    int pos = atomicAdd(&cur[b], 1);
    rec[pos] = ((unsigned int)s << 16) | (unsigned int)ld;
  }
}

// ---- passC: per-bucket CSR finalize (offs, dinv, col) ---------------------
__global__ __launch_bounds__(256) void passC_kernel(
    const unsigned int* __restrict__ rec, const int* __restrict__ bucketBase,
    const int* __restrict__ csrBase, int* __restrict__ offs,
    float* __restrict__ dinv, int* __restrict__ col, int n, int chunk) {
  int b = blockIdx.x;
  int tid = threadIdx.x;
  int d0 = b * chunk;
  if (d0 >= n) return;
  int nd = min(chunk, n - d0);
  int jb0 = bucketBase[b], jb1 = bucketBase[b + 1];
  int cb = csrBase[b];

  __shared__ int hist[NB];
  __shared__ int sc[NB];
  __shared__ int cursor[NB];
  hist[tid] = (tid < nd) ? 1 : 0;   // self-loop seed
  __syncthreads();
  for (int j = jb0 + tid; j < jb1; j += 256)
    atomicAdd(&hist[rec[j] & 0xFFFFu], 1);
  __syncthreads();
  int deg = hist[tid];
  sc[tid] = deg;
  __syncthreads();
  for (int off = 1; off < NB; off <<= 1) {
    int t = (tid >= off) ? sc[tid - off] : 0;
    __syncthreads();
    sc[tid] += t;
    __syncthreads();
  }
  int loc = sc[tid] - deg;          // exclusive prefix
  if (tid < nd) {
    offs[d0 + tid] = cb + loc;
    dinv[d0 + tid] = rsqrtf((float)deg);
    col[cb + loc] = d0 + tid;       // self-loop first
  }
  cursor[tid] = loc + 1;
  __syncthreads();
  for (int j = jb0 + tid; j < jb1; j += 256) {
    unsigned int r = rec[j];
    int ld = (int)(r & 0xFFFFu);
    int s  = (int)(r >> 16);
    int p = atomicAdd(&cursor[ld], 1);
    col[cb + p] = s;
  }
}

// ---- dense GEMM: T = H @ W; epilogue: bias+relu (fuse) / dinv-scale -------
// Writes fp32 to T32 if T16==nullptr, else fp16 to T16.
__global__ __launch_bounds__(256) void gemm_kernel(
    const float* __restrict__ H, const float* __restrict__ W,
    const float* __restrict__ bias, const float* __restrict__ dinv,
    float* __restrict__ T32, __half* __restrict__ T16, int n, int fuse) {
  __shared__ float Ws[64][68];
  __shared__ float Hs[64][68];
  int tid = threadIdx.x;
  int row0 = blockIdx.x * 64;

  for (int i = tid; i < 1024; i += 256) {
    int r = i >> 4, c = (i & 15) << 2;
    float4 wv = ((const float4*)W)[i];
    *reinterpret_cast<float4*>(&Ws[r][c]) = wv;
    float4 hv = make_float4(0.f, 0.f, 0.f, 0.f);
    if (row0 + r < n)
      hv = *reinterpret_cast<const float4*>(H + (size_t)(row0 + r) * DD + c);
    *reinterpret_cast<float4*>(&Hs[r][c]) = hv;
  }
  __syncthreads();

  int tr = tid >> 4, tc = tid & 15;
  int r0 = tr << 2, c0 = tc << 2;

  float acc[4][4];
#pragma unroll
  for (int i = 0; i < 4; ++i)
#pragma unroll
    for (int j = 0; j < 4; ++j) acc[i][j] = 0.f;

#pragma unroll
  for (int k = 0; k < 64; ++k) {
    float h0 = Hs[r0 + 0][k];
    float h1 = Hs[r0 + 1][k];
    float h2 = Hs[r0 + 2][k];
    float h3 = Hs[r0 + 3][k];
    float4 wv = *reinterpret_cast<const float4*>(&Ws[k][c0]);
    acc[0][0] = fmaf(h0, wv.x, acc[0][0]);
    acc[0][1] = fmaf(h0, wv.y, acc[0][1]);
    acc[0][2] = fmaf(h0, wv.z, acc[0][2]);
    acc[0][3] = fmaf(h0, wv.w, acc[0][3]);
    acc[1][0] = fmaf(h1, wv.x, acc[1][0]);
    acc[1][1] = fmaf(h1, wv.y, acc[1][1]);
    acc[1][2] = fmaf(h1, wv.z, acc[1][2]);
    acc[1][3] = fmaf(h1, wv.w, acc[1][3]);
    acc[2][0] = fmaf(h2, wv.x, acc[2][0]);
    acc[2][1] = fmaf(h2, wv.y, acc[2][1]);
    acc[2][2] = fmaf(h2, wv.z, acc[2][2]);
    acc[2][3] = fmaf(h2, wv.w, acc[2][3]);
    acc[3][0] = fmaf(h3, wv.x, acc[3][0]);
    acc[3][1] = fmaf(h3, wv.y, acc[3][1]);
    acc[3][2] = fmaf(h3, wv.z, acc[3][2]);
    acc[3][3] = fmaf(h3, wv.w, acc[3][3]);
  }

  float4 bv = make_float4(0.f, 0.f, 0.f, 0.f);
  if (fuse) bv = *reinterpret_cast<const float4*>(bias + c0);
#pragma unroll
  for (int i = 0; i < 4; ++i) {
    long long row = (long long)row0 + r0 + i;
    if (row >= n) break;
    float4 o = make_float4(acc[i][0], acc[i][1], acc[i][2], acc[i][3]);
    if (fuse) {
      o.x = fmaxf(o.x + bv.x, 0.f);
      o.y = fmaxf(o.y + bv.y, 0.f);
      o.z = fmaxf(o.z + bv.z, 0.f);
      o.w = fmaxf(o.w + bv.w, 0.f);
    }
    if (dinv) {
      float dv = dinv[row];
      o.x *= dv; o.y *= dv; o.z *= dv; o.w *= dv;
    }
    if (T16) {
      __half2 p01 = __floats2half2_rn(o.x, o.y);
      __half2 p23 = __floats2half2_rn(o.z, o.w);
      uint2 u;
      u.x = *reinterpret_cast<unsigned int*>(&p01);
      u.y = *reinterpret_cast<unsigned int*>(&p23);
      *reinterpret_cast<uint2*>(T16 + (size_t)row * DD + c0) = u;
    } else {
      *reinterpret_cast<float4*>(T32 + (size_t)row * DD + c0) = o;
    }
  }
}

// ---- CSR aggregation: out[d,:] = dinv[d] * sum_{c in N(d)} T16[c,:] + b ---
// one wave per node; lane = (row-group g = lane>>3, dim-slice s = lane&7).
// Wave-cooperative col preload (one coalesced 64-wide load per node),
// in-register index distribution via shfl, 4-deep independent row gathers.
__device__ __forceinline__ void acc8(float* acc, uint4 u) {
  __half2 h0 = *reinterpret_cast<__half2*>(&u.x);
  __half2 h1 = *reinterpret_cast<__half2*>(&u.y);
  __half2 h2 = *reinterpret_cast<__half2*>(&u.z);
  __half2 h3 = *reinterpret_cast<__half2*>(&u.w);
  float2 f0 = __half22float2(h0);
  float2 f1 = __half22float2(h1);
  float2 f2 = __half22float2(h2);
  float2 f3 = __half22float2(h3);
  acc[0] += f0.x; acc[1] += f0.y;
  acc[2] += f1.x; acc[3] += f1.y;
  acc[4] += f2.x; acc[5] += f2.y;
  acc[6] += f3.x; acc[7] += f3.y;
}

__global__ __launch_bounds__(256) void aggregate_kernel(
    const __half* __restrict__ T, const int* __restrict__ offs,
    const int* __restrict__ col, const float* __restrict__ dinv,
    const float* __restrict__ bias, float* __restrict__ out,
    int n, int relu) {
  int gid = blockIdx.x * blockDim.x + threadIdx.x;
  int wid = gid >> 6;
  if (wid >= n) return;
  int lane = threadIdx.x & 63;
  int g = lane >> 3;          // row group 0..7
  int s = lane & 7;           // dim slice: dims 8s..8s+7
  int j0 = offs[wid], j1 = offs[wid + 1];
  int deg = j1 - j0;
  const __half* Ts = T + s * 8;

  float acc[8];
#pragma unroll
  for (int k = 0; k < 8; ++k) acc[k] = 0.f;

  for (int base = 0; base < deg; base += 64) {
    int idx = base + lane;
    int c_local = (idx < deg) ? col[j0 + idx] : -1;
    int rem = deg - base; if (rem > 64) rem = 64;
    int nr = (rem + 7) >> 3;          // rounds in this batch (wave-uniform)
    int t = 0;
    for (; t + 4 <= nr; t += 4) {     // 4 rounds in flight
      int i = t * 8 + g;
      int c0 = __shfl(c_local, i, 64);
      int c1 = __shfl(c_local, i + 8, 64);
      int c2 = __shfl(c_local, i + 16, 64);
      int c3 = __shfl(c_local, i + 24, 64);
      // rounds t..t+2 are guaranteed full; only t+3 may be partial
      uint4 u0 = *reinterpret_cast<const uint4*>(Ts + (size_t)c0 * DD);
      uint4 u1 = *reinterpret_cast<const uint4*>(Ts + (size_t)c1 * DD);
      uint4 u2 = *reinterpret_cast<const uint4*>(Ts + (size_t)c2 * DD);
      if (c3 >= 0) {
        uint4 u3 = *reinterpret_cast<const uint4*>(Ts + (size_t)c3 * DD);
        acc8(acc, u3);
      }
      acc8(acc, u0);
      acc8(acc, u1);
      acc8(acc, u2);
    }
    for (; t < nr; ++t) {             // leftover rounds (masked)
      int i = t * 8 + g;
      int c = __shfl(c_local, i, 64);
      if (c >= 0) {
        uint4 u = *reinterpret_cast<const uint4*>(Ts + (size_t)c * DD);
        acc8(acc, u);
      }
    }
  }

  // reduce over g (lane bits 3,4,5)
#pragma unroll
  for (int m = 8; m <= 32; m <<= 1) {
#pragma unroll
    for (int k = 0; k < 8; ++k)
      acc[k] += __shfl_xor(acc[k], m, 64);
  }

  if (g == 0) {
    float dv = dinv[wid];
    const float4* bp = reinterpret_cast<const float4*>(bias + s * 8);
    float4 b0 = bp[0], b1 = bp[1];
    float4 o0, o1;
    o0.x = fmaf(acc[0], dv, b0.x);
    o0.y = fmaf(acc[1], dv, b0.y);
    o0.z = fmaf(acc[2], dv, b0.z);
    o0.w = fmaf(acc[3], dv, b0.w);
    o1.x = fmaf(acc[4], dv, b1.x);
    o1.y = fmaf(acc[5], dv, b1.y);
    o1.z = fmaf(acc[6], dv, b1.z);
    o1.w = fmaf(acc[7], dv, b1.w);
    if (relu) {
      o0.x = fmaxf(o0.x, 0.f); o0.y = fmaxf(o0.y, 0.f);
      o0.z = fmaxf(o0.z, 0.f); o0.w = fmaxf(o0.w, 0.f);
      o1.x = fmaxf(o1.x, 0.f); o1.y = fmaxf(o1.y, 0.f);
      o1.z = fmaxf(o1.z, 0.f); o1.w = fmaxf(o1.w, 0.f);
    }
    float4* op = reinterpret_cast<float4*>(out + (size_t)wid * DD + s * 8);
    op[0] = o0;
    op[1] = o1;
  }
}

// ---------------------------------------------------------------------------
extern "C" void kernel_launch(void* const* d_in, const int* in_sizes, int n_in,
                              void* d_out, int out_size, void* d_ws, size_t ws_size,
                              hipStream_t stream) {
  const float* x   = (const float*)d_in[0];
  const void*  eix = d_in[1];
  const float* Win = (const float*)d_in[2];
  const float* bin = (const float*)d_in[3];
  const float* W1  = (const float*)d_in[4];
  const float* b1  = (const float*)d_in[5];
  const float* W2  = (const float*)d_in[6];
  const float* b2  = (const float*)d_in[7];
  const float* W3  = (const float*)d_in[8];
  const float* b3  = (const float*)d_in[9];

  int n = in_sizes[0] / DD;
  int E = in_sizes[1] / 2;
  int M = E + n;
  int chunk = (n + NB - 1) / NB;    // local-dst fits 16 bits for n <= 65536

  char* w = (char*)d_ws;
  auto carve = [&](size_t bytes) {
    char* p = w;
    w += (bytes + 255) & ~(size_t)255;
    return p;
  };
  int*          histPB     = (int*)carve((size_t)GB * NB * 4);
  int*          localpre   = (int*)carve((size_t)NB * GB * 4);
  int*          tot        = (int*)carve((size_t)NB * 4);
  int*          bucketBase = (int*)carve((size_t)(NB + 1) * 4);
  int*          csrBase    = (int*)carve((size_t)NB * 4);
  int*          offs       = (int*)carve((size_t)(n + 1) * 4);
  float*        dinv       = (float*)carve((size_t)n * 4);
  unsigned int* rec        = (unsigned int*)carve((size_t)E * 4);
  int*          col        = (int*)carve((size_t)M * 4);
  float*        hbuf       = (float*)carve((size_t)n * DD * 4);
  __half*       t16        = (__half*)carve((size_t)n * DD * 2);

  histA_kernel<<<GB, 256, 0, stream>>>(eix, E, chunk, histPB);
  scanB1_kernel<<<NB, GB, 0, stream>>>(histPB, localpre, tot);
  scanB2_kernel<<<1, NB, 0, stream>>>(tot, bucketBase, csrBase, offs, n, chunk);
  passB_kernel<<<GB, 256, 0, stream>>>(eix, E, chunk, bucketBase, localpre, rec);
  passC_kernel<<<NB, 256, 0, stream>>>(rec, bucketBase, csrBase, offs, dinv,
                                       col, n, chunk);

  int gemm_grid = (n + 63) / 64;
  int agg_grid  = (n * 64 + 255) / 256;

  // layer 0: h = relu(x @ W_in + b_in)      (fp32 out, no dinv scale)
  gemm_kernel<<<gemm_grid, 256, 0, stream>>>(x, Win, bin, nullptr, hbuf, nullptr, n, 1);

  // conv1: h = relu(dinv*agg(fp16(dinv*(h @ W1))) + b1)
  gemm_kernel<<<gemm_grid, 256, 0, stream>>>(hbuf, W1, nullptr, dinv, nullptr, t16, n, 0);
  aggregate_kernel<<<agg_grid, 256, 0, stream>>>(t16, offs, col, dinv, b1, hbuf, n, 1);

  // conv2
  gemm_kernel<<<gemm_grid, 256, 0, stream>>>(hbuf, W2, nullptr, dinv, nullptr, t16, n, 0);
  aggregate_kernel<<<agg_grid, 256, 0, stream>>>(t16, offs, col, dinv, b2, hbuf, n, 1);

  // conv3 (no relu)
  gemm_kernel<<<gemm_grid, 256, 0, stream>>>(hbuf, W3, nullptr, dinv, nullptr, t16, n, 0);
  aggregate_kernel<<<agg_grid, 256, 0, stream>>>(t16, offs, col, dinv, b3, (float*)d_out, n, 0);
}